// Round 1
// baseline (186.859 us; speedup 1.0000x reference)
//
#include <hip/hip_runtime.h>

// S = 1024*1024, ranks [1,3,3,3,3,1].
#define SDIM (1024 * 1024)
#define NPLANE 10                 // TT0 (1 plane) + TT1..TT3 (3 planes each)
#define K1_THREADS 512
#define NBLK 512                  // K1 blocks; each covers SPAN_S s-values
#define SPAN_S 2048               // s-values per block (512 * 2048 = SDIM)
#define STREAM_F4 512             // float4 stride between the 3 coalesced streams

// K1: one block handles ALL 10 planes for one contiguous span of 2048 s-values.
// Plane data (flat e = 3s+q) is read as three perfectly-coalesced float4 streams
// (lane stride 16B), z staged once in LDS for all planes. Because 4 and 3 are
// coprime, each loaded float4 straddles q-phases; we accumulate into rotated
// accumulators B[p][(2m+j)%3] (compile-time indices) and un-rotate at the tail.
__global__ __launch_bounds__(K1_THREADS, 4) void ftt_k1(
    const float* __restrict__ z,
    const float* __restrict__ t0,
    const float* __restrict__ t1,
    const float* __restrict__ t2,
    const float* __restrict__ t3,
    float* __restrict__ partials)   // planar: [q][plane][NBLK]
{
    const int t = threadIdx.x;
    const int blk = blockIdx.x;

    // ---- stage z tile (coalesced, once for all 10 planes) ----
    __shared__ __align__(16) float zl[SPAN_S];
    reinterpret_cast<float4*>(zl)[t] =
        reinterpret_cast<const float4*>(z)[blk * (SPAN_S / 4) + t];
    __syncthreads();

    // ---- per-stream z values + phase-dependent selects (plane-invariant) ----
    // stream m covers flat elems e0 = 2048*m + 4*t .. +3 ; s0 = e0/3, r = e0%3.
    // elem j uses z[s0] if j < 3-r else z[s0+1]; j=0 -> always z0, j=3 -> always z1.
    float z0[3], z1[3], zB[3], zC[3];
    #pragma unroll
    for (int m = 0; m < 3; ++m) {
        const int e0 = 2048 * m + 4 * t;
        const int s0 = e0 / 3;
        const int r  = e0 % 3;                  // == (t + 2m) % 3
        z0[m] = zl[s0];
        z1[m] = zl[s0 + 1];                     // max index 2047: in-bounds
        zB[m] = (r <= 1) ? z0[m] : z1[m];       // j=1 factor
        zC[m] = (r == 0) ? z0[m] : z1[m];       // j=2 factor
    }

    float B[NPLANE][3];
    #pragma unroll
    for (int p = 0; p < NPLANE; ++p) { B[p][0] = 0.f; B[p][1] = 0.f; B[p][2] = 0.f; }

    const float* bases[NPLANE];
    bases[0] = t0;
    bases[1] = t1;  bases[2] = t1 + 3 * SDIM;  bases[3] = t1 + 6 * SDIM;
    bases[4] = t2;  bases[5] = t2 + 3 * SDIM;  bases[6] = t2 + 6 * SDIM;
    bases[7] = t3;  bases[8] = t3 + 3 * SDIM;  bases[9] = t3 + 6 * SDIM;
    const int off = blk * (SPAN_S * 3);          // flat float offset of this span

    #pragma unroll
    for (int p = 0; p < NPLANE; ++p) {
        const float4* pf = reinterpret_cast<const float4*>(bases[p] + off);
        const float4 v0 = pf[t];                  // stream m=0, phases k: 0,1,2
        const float4 v1 = pf[t + STREAM_F4];      // stream m=1, phases k: 2,0,1
        const float4 v2 = pf[t + 2 * STREAM_F4];  // stream m=2, phases k: 1,2,0
        // stream m, elem j -> B[(2m+j)%3]; j=0 and j=3 share the same slot.
        B[p][0] += v0.x * z0[0] + v0.w * z1[0];
        B[p][1] += v0.y * zB[0];
        B[p][2] += v0.z * zC[0];

        B[p][2] += v1.x * z0[1] + v1.w * z1[1];
        B[p][0] += v1.y * zB[1];
        B[p][1] += v1.z * zC[1];

        B[p][1] += v2.x * z0[2] + v2.w * z1[2];
        B[p][2] += v2.y * zB[2];
        B[p][0] += v2.z * zC[2];
    }

    // ---- un-rotate: true q of B[k] is (t + k) % 3  =>  a[q] = B[(q - t) mod 3] ----
    const int rT = t % 3;
    float a[NPLANE][3];
    #pragma unroll
    for (int p = 0; p < NPLANE; ++p) {
        a[p][0] = (rT == 0) ? B[p][0] : (rT == 1) ? B[p][2] : B[p][1];
        a[p][1] = (rT == 0) ? B[p][1] : (rT == 1) ? B[p][0] : B[p][2];
        a[p][2] = (rT == 0) ? B[p][2] : (rT == 1) ? B[p][1] : B[p][0];
    }

    // ---- wave (64) shuffle reduction of 30 values ----
    #pragma unroll
    for (int sh = 32; sh > 0; sh >>= 1) {
        #pragma unroll
        for (int p = 0; p < NPLANE; ++p) {
            a[p][0] += __shfl_down(a[p][0], sh, 64);
            a[p][1] += __shfl_down(a[p][1], sh, 64);
            a[p][2] += __shfl_down(a[p][2], sh, 64);
        }
    }

    __shared__ float red[K1_THREADS / 64][NPLANE * 3];
    const int lane = t & 63, wave = t >> 6;
    if (lane == 0) {
        #pragma unroll
        for (int p = 0; p < NPLANE; ++p) {
            red[wave][p * 3 + 0] = a[p][0];
            red[wave][p * 3 + 1] = a[p][1];
            red[wave][p * 3 + 2] = a[p][2];
        }
    }
    __syncthreads();
    if (t < NPLANE * 3) {
        const int p = t / 3, q = t % 3;
        float s = 0.f;
        #pragma unroll
        for (int w = 0; w < K1_THREADS / 64; ++w) s += red[w][t];
        partials[(q * NPLANE + p) * NBLK + blk] = s;
    }
}

// K2: reduce 30 planar rows of NBLK partials -> 30 sums -> f = V0@V1@V2@V3.
__global__ __launch_bounds__(256) void ftt_k2(
    const float* __restrict__ partials,
    float* __restrict__ fvec)
{
    __shared__ float red[32][9];            // 30 rows used; col pad for banks
    const int row = threadIdx.x >> 3;       // 0..31 (30 used) = q*NPLANE + p
    const int sub = threadIdx.x & 7;        // 8 threads per row
    if (row < NPLANE * 3) {
        const float4* pr = reinterpret_cast<const float4*>(partials + row * NBLK)
                           + sub * (NBLK / 4 / 8);
        float s0 = 0.f, s1 = 0.f, s2 = 0.f, s3 = 0.f;
        #pragma unroll
        for (int i = 0; i < NBLK / 4 / 8; ++i) {    // 16 float4 each, coalesced
            const float4 v = pr[i];
            s0 += v.x; s1 += v.y; s2 += v.z; s3 += v.w;
        }
        red[row][sub] = (s0 + s1) + (s2 + s3);
    }
    __syncthreads();

    if (threadIdx.x == 0) {
        float sum[NPLANE * 3];
        #pragma unroll
        for (int i = 0; i < NPLANE * 3; ++i) {
            float v = 0.f;
            #pragma unroll
            for (int g = 0; g < 8; ++g) v += red[i][g];
            sum[i] = v;
        }
        // f init = plane 0; then chain through cores k=1..3.
        // V_k[r][q] = sum[q*NPLANE + (1 + 3*(k-1) + r)]
        float f0 = sum[0], f1 = sum[NPLANE], f2 = sum[2 * NPLANE];
        #pragma unroll
        for (int k = 0; k < 3; ++k) {
            const int pb = 1 + k * 3;
            const float n0 = f0 * sum[0 * NPLANE + pb + 0] + f1 * sum[0 * NPLANE + pb + 1] + f2 * sum[0 * NPLANE + pb + 2];
            const float n1 = f0 * sum[1 * NPLANE + pb + 0] + f1 * sum[1 * NPLANE + pb + 1] + f2 * sum[1 * NPLANE + pb + 2];
            const float n2 = f0 * sum[2 * NPLANE + pb + 0] + f1 * sum[2 * NPLANE + pb + 1] + f2 * sum[2 * NPLANE + pb + 2];
            f0 = n0; f1 = n1; f2 = n2;
        }
        fvec[0] = f0; fvec[1] = f1; fvec[2] = f2;
    }
}

// K3: out[s] = f0*TT4[0,s,0] + f1*TT4[1,s,0] + f2*TT4[2,s,0]   (TT4 is (3,S,1))
__global__ __launch_bounds__(256) void ftt_k3(
    const float* __restrict__ t4,
    const float* __restrict__ fvec,
    float* __restrict__ out)
{
    const int i = blockIdx.x * blockDim.x + threadIdx.x;   // float4 index
    const float f0 = fvec[0], f1 = fvec[1], f2 = fvec[2];
    const float4 a = reinterpret_cast<const float4*>(t4)[i];
    const float4 b = reinterpret_cast<const float4*>(t4 + SDIM)[i];
    const float4 c = reinterpret_cast<const float4*>(t4 + 2 * SDIM)[i];
    float4 o;
    o.x = f0 * a.x + f1 * b.x + f2 * c.x;
    o.y = f0 * a.y + f1 * b.y + f2 * c.y;
    o.z = f0 * a.z + f1 * b.z + f2 * c.z;
    o.w = f0 * a.w + f1 * b.w + f2 * c.w;
    reinterpret_cast<float4*>(out)[i] = o;
}

extern "C" void kernel_launch(void* const* d_in, const int* in_sizes, int n_in,
                              void* d_out, int out_size, void* d_ws, size_t ws_size,
                              hipStream_t stream)
{
    const float* z  = (const float*)d_in[0];
    const float* t0 = (const float*)d_in[1];
    const float* t1 = (const float*)d_in[2];
    const float* t2 = (const float*)d_in[3];
    const float* t3 = (const float*)d_in[4];
    const float* t4 = (const float*)d_in[5];
    float* out = (float*)d_out;

    // partials (30*NBLK floats = 60 KB) live in d_out scratch space: K2 consumes
    // them before K3 overwrites the whole output buffer. Workspace only holds fvec.
    float* partials = (float*)d_out;
    float* fvec     = (float*)d_ws;

    ftt_k1<<<NBLK, K1_THREADS, 0, stream>>>(z, t0, t1, t2, t3, partials);
    ftt_k2<<<1, 256, 0, stream>>>(partials, fvec);
    ftt_k3<<<SDIM / 4 / 256, 256, 0, stream>>>(t4, fvec, out);
}

// Round 2
// 169.448 us; speedup vs baseline: 1.1028x; 1.1028x over previous
//
#include <hip/hip_runtime.h>

// S = 1024*1024, ranks [1,3,3,3,3,1].
#define SDIM (1024 * 1024)
#define GROUPS (SDIM / 4)            // float4 groups of s (262144)
#define GPT 8                        // float4-groups per thread in K1
#define CHUNKS (GROUPS / (256 * GPT))// 128 chunks per plane
#define NPLANE 10                    // TT0 (1 plane) + TT1..TT3 (3 planes each)

// K1: grid (CHUNKS, NPLANE). Each block computes a partial 3-vector:
//   part[plane][chunk][q] = sum_{s in chunk} z[s] * plane[s*3 + q]
// Round-0 structure (proven): each lane reads its z float4 + 48B of contiguous
// plane data per iteration. Round-2 changes:
//   - GPT 4 -> 8: the 18-shuffle reduction tail is paid per 32 loads, not 16.
//   - depth-2 software pipeline: iteration it+1's 4 loads are issued before
//     iteration it's FMAs, doubling loads-in-flight per wave (~8) so the wave
//     doesn't stall on vmcnt every iteration. Costs ~16 extra VGPRs (<64).
__global__ __launch_bounds__(256) void ftt_k1(
    const float* __restrict__ z,
    const float* __restrict__ t0,
    const float* __restrict__ t1,
    const float* __restrict__ t2,
    const float* __restrict__ t3,
    float* __restrict__ partials)   // [NPLANE][CHUNKS][4]
{
    const int plane = blockIdx.y;

    const float* base;
    if (plane == 0) {
        base = t0;
    } else {
        const int pk = plane - 1;
        const int k = pk / 3;                        // wave-uniform
        const float* tk = (k == 0) ? t1 : (k == 1) ? t2 : t3;
        base = tk + (pk % 3) * (3 * SDIM);
    }

    const float4* zf4 = reinterpret_cast<const float4*>(z);
    const float4* bf4 = reinterpret_cast<const float4*>(base);

    const int g0 = blockIdx.x * (256 * GPT) + threadIdx.x;
    float a0 = 0.0f, a1 = 0.0f, a2 = 0.0f;

    // prologue: issue iteration 0's loads
    float4 z4 = zf4[g0];
    float4 c0 = bf4[3 * g0 + 0];
    float4 c1 = bf4[3 * g0 + 1];
    float4 c2 = bf4[3 * g0 + 2];

    #pragma unroll
    for (int it = 0; it < GPT; ++it) {
        float4 zn{}, n0{}, n1{}, n2{};
        if (it + 1 < GPT) {                       // compile-time after unroll
            const int g = g0 + (it + 1) * 256;
            zn = zf4[g];
            n0 = bf4[3 * g + 0];
            n1 = bf4[3 * g + 1];
            n2 = bf4[3 * g + 2];
        }
        // acc[q] += sum_j z_j * tt[3j+q]; tt flat = c0.xyzw c1.xyzw c2.xyzw
        a0 += z4.x * c0.x + z4.y * c0.w + z4.z * c1.z + z4.w * c2.y;
        a1 += z4.x * c0.y + z4.y * c1.x + z4.z * c1.w + z4.w * c2.z;
        a2 += z4.x * c0.z + z4.y * c1.y + z4.z * c2.x + z4.w * c2.w;
        if (it + 1 < GPT) { z4 = zn; c0 = n0; c1 = n1; c2 = n2; }
    }

    // wave (64) shuffle reduction
    #pragma unroll
    for (int off = 32; off > 0; off >>= 1) {
        a0 += __shfl_down(a0, off, 64);
        a1 += __shfl_down(a1, off, 64);
        a2 += __shfl_down(a2, off, 64);
    }

    __shared__ float red[4][3];
    const int lane = threadIdx.x & 63;
    const int wave = threadIdx.x >> 6;
    if (lane == 0) { red[wave][0] = a0; red[wave][1] = a1; red[wave][2] = a2; }
    __syncthreads();
    if (threadIdx.x < 3) {
        const int c = threadIdx.x;
        const float s = red[0][c] + red[1][c] + red[2][c] + red[3][c];
        partials[(plane * CHUNKS + blockIdx.x) * 4 + c] = s;
    }
}

// K2: reduce [NPLANE][CHUNKS] partial triples -> 30 sums -> f = V0@V1@V2@V3 (3 floats)
__global__ __launch_bounds__(256) void ftt_k2(
    const float* __restrict__ partials,
    float* __restrict__ fvec)
{
    __shared__ float red[NPLANE * 3][8];
    const int job = threadIdx.x >> 3;   // 0..31 (30 used): job = plane*3 + c
    const int sub = threadIdx.x & 7;    // 8 threads per job, CHUNKS/8 chunks each
    if (job < NPLANE * 3) {
        const int plane = job / 3, c = job % 3;
        float s = 0.0f;
        const int b0 = sub * (CHUNKS / 8);
        #pragma unroll 4
        for (int b = b0; b < b0 + (CHUNKS / 8); ++b)
            s += partials[(plane * CHUNKS + b) * 4 + c];
        red[job][sub] = s;
    }
    __syncthreads();

    if (threadIdx.x == 0) {
        float sum[NPLANE * 3];
        #pragma unroll
        for (int i = 0; i < NPLANE * 3; ++i) {
            float t = 0.0f;
            #pragma unroll
            for (int g = 0; g < 8; ++g) t += red[i][g];
            sum[i] = t;
        }
        float f0 = sum[0], f1 = sum[1], f2 = sum[2];
        #pragma unroll
        for (int k = 0; k < 3; ++k) {
            const float* V = &sum[3 + k * 9];   // V[r*3+q]
            const float n0 = f0 * V[0] + f1 * V[3] + f2 * V[6];
            const float n1 = f0 * V[1] + f1 * V[4] + f2 * V[7];
            const float n2 = f0 * V[2] + f1 * V[5] + f2 * V[8];
            f0 = n0; f1 = n1; f2 = n2;
        }
        fvec[0] = f0; fvec[1] = f1; fvec[2] = f2;
    }
}

// K3: out[s] = f0*TT4[0,s] + f1*TT4[1,s] + f2*TT4[2,s]   (TT4 is (3,S,1))
__global__ __launch_bounds__(256) void ftt_k3(
    const float* __restrict__ t4,
    const float* __restrict__ fvec,
    float* __restrict__ out)
{
    const int i = blockIdx.x * blockDim.x + threadIdx.x;   // float4 index
    const float f0 = fvec[0], f1 = fvec[1], f2 = fvec[2];
    const float4 a = reinterpret_cast<const float4*>(t4)[i];
    const float4 b = reinterpret_cast<const float4*>(t4 + SDIM)[i];
    const float4 c = reinterpret_cast<const float4*>(t4 + 2 * SDIM)[i];
    float4 o;
    o.x = f0 * a.x + f1 * b.x + f2 * c.x;
    o.y = f0 * a.y + f1 * b.y + f2 * c.y;
    o.z = f0 * a.z + f1 * b.z + f2 * c.z;
    o.w = f0 * a.w + f1 * b.w + f2 * c.w;
    reinterpret_cast<float4*>(out)[i] = o;
}

extern "C" void kernel_launch(void* const* d_in, const int* in_sizes, int n_in,
                              void* d_out, int out_size, void* d_ws, size_t ws_size,
                              hipStream_t stream)
{
    const float* z  = (const float*)d_in[0];
    const float* t0 = (const float*)d_in[1];
    const float* t1 = (const float*)d_in[2];
    const float* t2 = (const float*)d_in[3];
    const float* t3 = (const float*)d_in[4];
    const float* t4 = (const float*)d_in[5];
    float* out = (float*)d_out;

    float* partials = (float*)d_ws;                      // NPLANE*CHUNKS*4 floats
    float* fvec     = partials + NPLANE * CHUNKS * 4;    // 3 floats

    ftt_k1<<<dim3(CHUNKS, NPLANE), 256, 0, stream>>>(z, t0, t1, t2, t3, partials);
    ftt_k2<<<1, 256, 0, stream>>>(partials, fvec);
    ftt_k3<<<SDIM / 4 / 256, 256, 0, stream>>>(t4, fvec, out);
}

// Round 3
// 166.963 us; speedup vs baseline: 1.1192x; 1.0149x over previous
//
#include <hip/hip_runtime.h>

// S = 1024*1024, ranks [1,3,3,3,3,1].
#define SDIM (1024 * 1024)
#define GROUPS (SDIM / 4)            // float4 groups of s (262144)
#define GPT 4                        // float4-groups per thread in K1
#define CHUNKS (GROUPS / (256 * GPT))// 256 chunks per plane
#define NPLANE 10                    // TT0 (1 plane) + TT1..TT3 (3 planes each)

// K1: grid (CHUNKS, NPLANE). Each block computes a partial 3-vector:
//   part[plane][chunk][q] = sum_{s in chunk} z[s] * plane[s*3 + q]
// Round-3 change: ALL 16 loads (4 iters x {z4,c0,c1,c2}) are issued into named
// registers, then a sched_barrier(0) fence stops hipcc from sinking them to
// just-before-use (round-2 post-mortem: VGPR=36 proved the compiler kept only
// ~4 loads in flight and serialized the wave on vmcnt). 16-deep per-wave MLP
// at ~84 VGPR (6 waves/SIMD) vs 4-deep at 8 waves: net ~3x memory parallelism.
__global__ __launch_bounds__(256) void ftt_k1(
    const float* __restrict__ z,
    const float* __restrict__ t0,
    const float* __restrict__ t1,
    const float* __restrict__ t2,
    const float* __restrict__ t3,
    float* __restrict__ partials)   // [NPLANE][CHUNKS][4]
{
    const int plane = blockIdx.y;

    const float* base;
    if (plane == 0) {
        base = t0;
    } else {
        const int pk = plane - 1;
        const int k = pk / 3;                        // wave-uniform
        const float* tk = (k == 0) ? t1 : (k == 1) ? t2 : t3;
        base = tk + (pk % 3) * (3 * SDIM);
    }

    const float4* zf4 = reinterpret_cast<const float4*>(z);
    const float4* bf4 = reinterpret_cast<const float4*>(base);

    const int g0 = blockIdx.x * (256 * GPT) + threadIdx.x;

    // ---- issue all 16 loads back-to-back (16 outstanding per wave) ----
    float4 L[GPT][4];
    #pragma unroll
    for (int it = 0; it < GPT; ++it) {
        const int g = g0 + it * 256;
        L[it][0] = zf4[g];
        L[it][1] = bf4[3 * g + 0];
        L[it][2] = bf4[3 * g + 1];
        L[it][3] = bf4[3 * g + 2];
    }
    __builtin_amdgcn_sched_barrier(0);   // loads may not sink past this point

    // ---- consume ----
    float a0 = 0.0f, a1 = 0.0f, a2 = 0.0f;
    #pragma unroll
    for (int it = 0; it < GPT; ++it) {
        const float4 z4 = L[it][0];
        const float4 c0 = L[it][1];
        const float4 c1 = L[it][2];
        const float4 c2 = L[it][3];
        // acc[q] += sum_j z_j * tt[3j+q]; tt flat = c0.xyzw c1.xyzw c2.xyzw
        a0 += z4.x * c0.x + z4.y * c0.w + z4.z * c1.z + z4.w * c2.y;
        a1 += z4.x * c0.y + z4.y * c1.x + z4.z * c1.w + z4.w * c2.z;
        a2 += z4.x * c0.z + z4.y * c1.y + z4.z * c2.x + z4.w * c2.w;
    }

    // wave (64) shuffle reduction
    #pragma unroll
    for (int off = 32; off > 0; off >>= 1) {
        a0 += __shfl_down(a0, off, 64);
        a1 += __shfl_down(a1, off, 64);
        a2 += __shfl_down(a2, off, 64);
    }

    __shared__ float red[4][3];
    const int lane = threadIdx.x & 63;
    const int wave = threadIdx.x >> 6;
    if (lane == 0) { red[wave][0] = a0; red[wave][1] = a1; red[wave][2] = a2; }
    __syncthreads();
    if (threadIdx.x < 3) {
        const int c = threadIdx.x;
        const float s = red[0][c] + red[1][c] + red[2][c] + red[3][c];
        partials[(plane * CHUNKS + blockIdx.x) * 4 + c] = s;
    }
}

// K2: reduce [NPLANE][CHUNKS] partial triples -> 30 sums -> f = V0@V1@V2@V3 (3 floats)
__global__ __launch_bounds__(256) void ftt_k2(
    const float* __restrict__ partials,
    float* __restrict__ fvec)
{
    __shared__ float red[NPLANE * 3][8];
    const int job = threadIdx.x >> 3;   // 0..31 (30 used): job = plane*3 + c
    const int sub = threadIdx.x & 7;    // 8 threads per job, CHUNKS/8 chunks each
    if (job < NPLANE * 3) {
        const int plane = job / 3, c = job % 3;
        float s = 0.0f;
        const int b0 = sub * (CHUNKS / 8);
        #pragma unroll 4
        for (int b = b0; b < b0 + (CHUNKS / 8); ++b)
            s += partials[(plane * CHUNKS + b) * 4 + c];
        red[job][sub] = s;
    }
    __syncthreads();

    if (threadIdx.x == 0) {
        float sum[NPLANE * 3];
        #pragma unroll
        for (int i = 0; i < NPLANE * 3; ++i) {
            float t = 0.0f;
            #pragma unroll
            for (int g = 0; g < 8; ++g) t += red[i][g];
            sum[i] = t;
        }
        float f0 = sum[0], f1 = sum[1], f2 = sum[2];
        #pragma unroll
        for (int k = 0; k < 3; ++k) {
            const float* V = &sum[3 + k * 9];   // V[r*3+q]
            const float n0 = f0 * V[0] + f1 * V[3] + f2 * V[6];
            const float n1 = f0 * V[1] + f1 * V[4] + f2 * V[7];
            const float n2 = f0 * V[2] + f1 * V[5] + f2 * V[8];
            f0 = n0; f1 = n1; f2 = n2;
        }
        fvec[0] = f0; fvec[1] = f1; fvec[2] = f2;
    }
}

// K3: out[s] = f0*TT4[0,s] + f1*TT4[1,s] + f2*TT4[2,s]   (TT4 is (3,S,1))
__global__ __launch_bounds__(256) void ftt_k3(
    const float* __restrict__ t4,
    const float* __restrict__ fvec,
    float* __restrict__ out)
{
    const int i = blockIdx.x * blockDim.x + threadIdx.x;   // float4 index
    const float f0 = fvec[0], f1 = fvec[1], f2 = fvec[2];
    const float4 a = reinterpret_cast<const float4*>(t4)[i];
    const float4 b = reinterpret_cast<const float4*>(t4 + SDIM)[i];
    const float4 c = reinterpret_cast<const float4*>(t4 + 2 * SDIM)[i];
    float4 o;
    o.x = f0 * a.x + f1 * b.x + f2 * c.x;
    o.y = f0 * a.y + f1 * b.y + f2 * c.y;
    o.z = f0 * a.z + f1 * b.z + f2 * c.z;
    o.w = f0 * a.w + f1 * b.w + f2 * c.w;
    reinterpret_cast<float4*>(out)[i] = o;
}

extern "C" void kernel_launch(void* const* d_in, const int* in_sizes, int n_in,
                              void* d_out, int out_size, void* d_ws, size_t ws_size,
                              hipStream_t stream)
{
    const float* z  = (const float*)d_in[0];
    const float* t0 = (const float*)d_in[1];
    const float* t1 = (const float*)d_in[2];
    const float* t2 = (const float*)d_in[3];
    const float* t3 = (const float*)d_in[4];
    const float* t4 = (const float*)d_in[5];
    float* out = (float*)d_out;

    float* partials = (float*)d_ws;                      // NPLANE*CHUNKS*4 floats
    float* fvec     = partials + NPLANE * CHUNKS * 4;    // 3 floats

    ftt_k1<<<dim3(CHUNKS, NPLANE), 256, 0, stream>>>(z, t0, t1, t2, t3, partials);
    ftt_k2<<<1, 256, 0, stream>>>(partials, fvec);
    ftt_k3<<<SDIM / 4 / 256, 256, 0, stream>>>(t4, fvec, out);
}